// Round 1
// 1004.360 us; speedup vs baseline: 1.1014x; 1.1014x over previous
//
#include <hip/hip_runtime.h>
#include <stdint.h>

// ---------------------------------------------------------------------------
// Host copy of exact JAX Threefry-2x32 (jax/_src/prng.py; Random123 constants)
// used only to derive rkey = fold_in(key(42), 0) on the host.
// ---------------------------------------------------------------------------
static inline void threefry2x32_host(uint32_t k0, uint32_t k1,
                                     uint32_t x0, uint32_t x1,
                                     uint32_t& o0, uint32_t& o1) {
  const uint32_t ks2 = k0 ^ k1 ^ 0x1BD11BDAu;
#define TF_ROUND(r) { x0 += x1; x1 = (x1 << (r)) | (x1 >> (32 - (r))); x1 ^= x0; }
  x0 += k0; x1 += k1;
  TF_ROUND(13) TF_ROUND(15) TF_ROUND(26) TF_ROUND(6)
  x0 += k1;  x1 += ks2 + 1u;
  TF_ROUND(17) TF_ROUND(29) TF_ROUND(16) TF_ROUND(24)
  x0 += ks2; x1 += k0 + 2u;
  TF_ROUND(13) TF_ROUND(15) TF_ROUND(26) TF_ROUND(6)
  x0 += k0;  x1 += k1 + 3u;
  TF_ROUND(17) TF_ROUND(29) TF_ROUND(16) TF_ROUND(24)
  x0 += k1;  x1 += ks2 + 4u;
  TF_ROUND(13) TF_ROUND(15) TF_ROUND(26) TF_ROUND(6)
  x0 += ks2; x1 += k0 + 5u;
#undef TF_ROUND
  o0 = x0; o1 = x1;
}

// ---------------------------------------------------------------------------
// Device: jax partitionable 32-bit draw for counter ctr (< 2^32).
// Caller passes x1 = ctr + k1 (the initial key add, strength-reduced).
// x0's initial add collapses to x0 = k0 since the high counter word is 0.
// Every rotate is __builtin_rotateleft32 -> guaranteed v_alignbit_b32.
// Minimal form: 20*(add,alignbit,xor) + 10 injection adds + final xor.
// ---------------------------------------------------------------------------
__device__ __forceinline__ uint32_t tf_bits(uint32_t x1, uint32_t k0,
                                            uint32_t k1, uint32_t ks2) {
  uint32_t x0 = k0;
#define R4(a,b,c,d)                                              \
  x0 += x1; x1 = __builtin_rotateleft32(x1, a); x1 ^= x0;        \
  x0 += x1; x1 = __builtin_rotateleft32(x1, b); x1 ^= x0;        \
  x0 += x1; x1 = __builtin_rotateleft32(x1, c); x1 ^= x0;        \
  x0 += x1; x1 = __builtin_rotateleft32(x1, d); x1 ^= x0;
  R4(13, 15, 26, 6)
  x0 += k1;  x1 += ks2 + 1u;
  R4(17, 29, 16, 24)
  x0 += ks2; x1 += k0 + 2u;
  R4(13, 15, 26, 6)
  x0 += k0;  x1 += k1 + 3u;
  R4(17, 29, 16, 24)
  x0 += k1;  x1 += ks2 + 4u;
  R4(13, 15, 26, 6)
  x0 += ks2; x1 += k0 + 5u;
#undef R4
  return x0 ^ x1;  // bits = o0 ^ o1 (partitionable stream)
}

// quantize one value, bit-exact vs JAX:
//   r = bitcast((bits>>9)|0x3f800000) - 1   (exact subtraction, f in [1,2))
//   temp = floor(v*inv_sigma + r) * sigma   (v*inv_sigma exact: pow-2 scale,
//                                            so fma == mul+add bit-exactly)
//   clip(temp, tmin, tmax)                  (fmin(fmax(...)) -> v_med3_f32)
__device__ __forceinline__ float qround(float v, uint32_t bits, float sigma,
                                        float inv_sigma, float tmin, float tmax) {
  float r = __uint_as_float((bits >> 9) | 0x3f800000u) - 1.0f;
  float t = floorf(__builtin_fmaf(v, inv_sigma, r)) * sigma;
  return fminf(fmaxf(t, tmin), tmax);
}

// ---------------------------------------------------------------------------
// Kernel A: overflow/underflow counts at sigma0 thresholds.
// Wave-level counting: 16 ballots (1 v_cmp each) + SALU popcount/adds,
// one conditional atomic per wave (counts are 0 for sane data -> no atomics).
// ---------------------------------------------------------------------------
__global__ __launch_bounds__(256) void count_kernel(
    const float4* __restrict__ x4, const float* __restrict__ x,
    long long n4, long long n, unsigned int* __restrict__ counts,
    float tmax, float tmin, float htmax, float htmin) {
  long long i = (long long)blockIdx.x * 256 + threadIdx.x;
  unsigned int over = 0, under = 0;
  if (i < n4) {
    float4 v = x4[i];
    over  = __popcll(__ballot(v.x > tmax))  + __popcll(__ballot(v.x < tmin))
          + __popcll(__ballot(v.y > tmax))  + __popcll(__ballot(v.y < tmin))
          + __popcll(__ballot(v.z > tmax))  + __popcll(__ballot(v.z < tmin))
          + __popcll(__ballot(v.w > tmax))  + __popcll(__ballot(v.w < tmin));
    under = __popcll(__ballot(v.x > htmax)) + __popcll(__ballot(v.x < htmin))
          + __popcll(__ballot(v.y > htmax)) + __popcll(__ballot(v.y < htmin))
          + __popcll(__ballot(v.z > htmax)) + __popcll(__ballot(v.z < htmin))
          + __popcll(__ballot(v.w > htmax)) + __popcll(__ballot(v.w < htmin));
  }
  // lane 0 of each wave holds the wave total (lane 0 active iff any lane is)
  if ((threadIdx.x & 63) == 0) {
    if (over)  atomicAdd(&counts[0], over);
    if (under) atomicAdd(&counts[1], under);
  }
  // generic scalar tail (n % 4 != 0) -- never taken for n = 2^27
  if (i == 0 && (n & 3)) {
    unsigned int o2 = 0, u2 = 0;
    for (long long j = n4 << 2; j < n; ++j) {
      float v = x[j];
      o2 += (v > tmax)  + (v < tmin);
      u2 += (v > htmax) + (v < htmin);
    }
    if (o2) atomicAdd(&counts[0], o2);
    if (u2) atomicAdd(&counts[1], u2);
  }
}

// ---------------------------------------------------------------------------
// Kernel B: compute sigma from counts (uniform -> SALU + s_load), then
// stochastic-round. One float4 per thread, no loop, exact grid.
// ---------------------------------------------------------------------------
__global__ __launch_bounds__(256) void quant_kernel(
    const float4* __restrict__ x4, float4* __restrict__ o4,
    const float* __restrict__ x, float* __restrict__ out,
    long long n4, long long n, const unsigned int* __restrict__ counts,
    float inv_n, uint32_t k0, uint32_t k1) {
  const uint32_t ks2 = k0 ^ k1 ^ 0x1BD11BDAu;   // uniform -> SALU
  float overflow  = (float)counts[0] * inv_n;    // exact: inv_n = 2^-27
  float underflow = (float)counts[1] * inv_n;
  // sigma = where(over > .01, 2s, where(under < .01, s/2, s)), s = 0.25
  float sigma = (overflow > 0.01f) ? 0.5f
              : ((underflow < 0.01f) ? 0.125f : 0.25f);
  float tmax = sigma * 128.0f - sigma;
  float tmin = sigma * -128.0f;
  float inv_sigma = 1.0f / sigma;                // exact pow-2

  long long i = (long long)blockIdx.x * 256 + threadIdx.x;
  if (i < n4) {
    float4 v = x4[i];
    // counters 4i..4i+3; x1_init = ctr + k1, strength-reduced:
    uint32_t s = ((uint32_t)i << 2) + k1;        // one v_lshl_add_u32
    uint32_t b0 = tf_bits(s + 0u, k0, k1, ks2);
    uint32_t b1 = tf_bits(s + 1u, k0, k1, ks2);
    uint32_t b2 = tf_bits(s + 2u, k0, k1, ks2);
    uint32_t b3 = tf_bits(s + 3u, k0, k1, ks2);
    v.x = qround(v.x, b0, sigma, inv_sigma, tmin, tmax);
    v.y = qround(v.y, b1, sigma, inv_sigma, tmin, tmax);
    v.z = qround(v.z, b2, sigma, inv_sigma, tmin, tmax);
    v.w = qround(v.w, b3, sigma, inv_sigma, tmin, tmax);
    o4[i] = v;
  }
  // generic scalar tail -- never taken for n = 2^27
  if (i == 0 && (n & 3)) {
    for (long long j = n4 << 2; j < n; ++j) {
      uint32_t b = tf_bits((uint32_t)j + k1, k0, k1, ks2);
      out[j] = qround(x[j], b, sigma, inv_sigma, tmin, tmax);
    }
  }
}

extern "C" void kernel_launch(void* const* d_in, const int* in_sizes, int n_in,
                              void* d_out, int out_size, void* d_ws, size_t ws_size,
                              hipStream_t stream) {
  const float* x = (const float*)d_in[0];
  float* out = (float*)d_out;
  long long n = (long long)in_sizes[0];   // 134217728 = 2^27 elements

  unsigned int* counts = (unsigned int*)d_ws;
  hipMemsetAsync(counts, 0, 2 * sizeof(unsigned int), stream);

  // rkey = fold_in(key(42), 0) = threefry((0,42), (0,0)) -- config-independent
  uint32_t k0, k1;
  threefry2x32_host(0u, 42u, 0u, 0u, k0, k1);

  const float sigma0 = 0.25f;
  const float tmax0 = sigma0 * 128.0f - sigma0;   // 31.75
  const float tmin0 = -sigma0 * 128.0f;           // -32
  const float htmax0 = 0.5f * tmax0;              // 15.875
  const float htmin0 = 0.5f * tmin0;              // -16

  long long n4 = n >> 2;
  long long grid = (n4 + 255) / 256;
  if (grid < 1) grid = 1;                          // thread 0 must exist (tail)

  count_kernel<<<(dim3)(unsigned)grid, 256, 0, stream>>>(
      (const float4*)x, x, n4, n, counts, tmax0, tmin0, htmax0, htmin0);

  float inv_n = 1.0f / (float)n;
  quant_kernel<<<(dim3)(unsigned)grid, 256, 0, stream>>>(
      (const float4*)x, (float4*)out, x, out, n4, n, counts, inv_n, k0, k1);
}